// Round 2
// 571.387 us; speedup vs baseline: 1.0251x; 1.0251x over previous
//
#include <hip/hip_runtime.h>
#include <math.h>

#define NPTS 262144
#define TTAB 524288
#define TMASK (TTAB - 1)
#define PR1 2654435761u
#define PR2 805459861u

// merged-table hash: 16 levels x 256 chunks, 2 levels per XCD queue
#define MQ_SLOTS 512
#define MHASH_BLOCKS (8 * MQ_SLOTS)
// fp32 fallback path (ws too small): 48 pairs x 256 chunks
#define FQ_SLOTS 1536
#define FHASH_BLOCKS (8 * FQ_SLOTS)

typedef __attribute__((ext_vector_type(4))) float f32x4;
typedef __attribute__((ext_vector_type(8))) short bf16x8;
typedef __attribute__((ext_vector_type(3))) unsigned int uintx3;

struct ResArr { float r[16]; };

__device__ __forceinline__ float bf2f(unsigned int u) {
  union { unsigned int i; float f; } v; v.i = u << 16; return v.f;
}
__device__ __forceinline__ unsigned short f2bf(float f) {
  union { float f; unsigned int i; } v; v.f = f;
  unsigned int r = v.i + 0x7FFFu + ((v.i >> 16) & 1u);
  return (unsigned short)(r >> 16);
}
__device__ __forceinline__ unsigned int pack2(float a, float b) {
  return (unsigned int)f2bf(a) | ((unsigned int)f2bf(b) << 16);
}

union U8 { uint4 u; bf16x8 v; };

// ---------------------------------------------------------------------------
// Tables fp32 -> merged packed-bf16: mt[(l*TTAB+idx)*3 + {sdf,color,sem}]
// One 12B entry holds all 3 tables' features for (level, idx).
// ---------------------------------------------------------------------------
__global__ __launch_bounds__(256) void cvt_tab(
    const float* __restrict__ t0, const float* __restrict__ t1,
    const float* __restrict__ t2, unsigned int* __restrict__ mt)
{
  size_t i = (size_t)blockIdx.x * 256 + threadIdx.x;   // l*TTAB + idx
  float2 a = ((const float2*)t0)[i];
  float2 b = ((const float2*)t1)[i];
  float2 c = ((const float2*)t2)[i];
  mt[i * 3 + 0] = pack2(a.x, a.y);
  mt[i * 3 + 1] = pack2(b.x, b.y);
  mt[i * 3 + 2] = pack2(c.x, c.y);
}

// ---------------------------------------------------------------------------
// Merged hash gather: one level per block-claim, XCD-affine queues.
// 8 x 12B dwordx3 gathers per point serve all 3 tables (3x fewer L2
// requests than per-table gathers). Level-major packed-bf16 features out.
// ---------------------------------------------------------------------------
__global__ __launch_bounds__(256) void hash_merged(
    const float* __restrict__ p, const float* __restrict__ bound,
    const unsigned int* __restrict__ mt,
    unsigned int* __restrict__ featws, unsigned int* __restrict__ ctr,
    ResArr res)
{
  __shared__ int s_slot;
  if (threadIdx.x == 0) {
    unsigned int xcc;
    asm volatile("s_getreg_b32 %0, hwreg(HW_REG_XCC_ID)" : "=s"(xcc));
    xcc &= 7u;
    int slot = -1;
    for (int k = 0; k < 8; ++k) {
      unsigned int q = (xcc + (unsigned int)k) & 7u;
      unsigned int s = atomicAdd(ctr + q, 1u);
      if (s < MQ_SLOTS) { slot = (int)(q * MQ_SLOTS + s); break; }
    }
    s_slot = slot;
  }
  __syncthreads();
  int slot = s_slot;
  if (slot < 0) return;

  unsigned int q = (unsigned int)slot / MQ_SLOTS;
  unsigned int s = (unsigned int)slot - q * MQ_SLOTS;
  unsigned int level = (s >> 8) * 8u + q;        // 0..15, queue q gets {q, q+8}
  unsigned int chunk = s & 255u;

  float r = res.r[0];
#pragma unroll
  for (int l = 1; l < 16; ++l) r = (level == (unsigned int)l) ? res.r[l] : r;

  float b0 = bound[0], b1 = bound[1], b2 = bound[2], b3 = bound[3],
        b4 = bound[4], b5 = bound[5];
  float i0v = 1.f / (b1 - b0), i1v = 1.f / (b3 - b2), i2v = 1.f / (b5 - b4);
  const unsigned int* mtl = mt + (size_t)level * TTAB * 3u;
  unsigned int f0 = (0u * 16u + level) * (unsigned int)NPTS;
  unsigned int f1 = (1u * 16u + level) * (unsigned int)NPTS;
  unsigned int f2b = (2u * 16u + level) * (unsigned int)NPTS;
  unsigned int nbase = chunk * 1024u + threadIdx.x;

#pragma unroll
  for (int half = 0; half < 2; ++half) {
    unsigned int CX[2], CY[2], CZ[2];
    float DX[2], DY[2], DZ[2];
#pragma unroll
    for (int pt = 0; pt < 2; ++pt) {
      unsigned int n = nbase + (unsigned int)(half * 512 + pt * 256);
      float px = p[n * 3 + 0], py = p[n * 3 + 1], pz = p[n * 3 + 2];
      float sx = (px - b0) * i0v * r;
      float sy = (py - b2) * i1v * r;
      float sz = (pz - b4) * i2v * r;
      float fx = floorf(sx), fy = floorf(sy), fz = floorf(sz);
      DX[pt] = sx - fx; DY[pt] = sy - fy; DZ[pt] = sz - fz;
      CX[pt] = (unsigned int)fx;
      CY[pt] = (unsigned int)fy * PR1;
      CZ[pt] = (unsigned int)fz * PR2;
    }
    __builtin_amdgcn_sched_barrier(0);

    uintx3 V[2][8];
#pragma unroll
    for (int pt = 0; pt < 2; ++pt) {
      unsigned int x0 = CX[pt], x1 = CX[pt] + 1u;
      unsigned int y0 = CY[pt], y1 = y0 + PR1;
      unsigned int z0 = CZ[pt], z1 = z0 + PR2;
      unsigned int id[8];
      id[0] = (x0 ^ y0 ^ z0) & TMASK;
      id[1] = (x0 ^ y0 ^ z1) & TMASK;
      id[2] = (x0 ^ y1 ^ z0) & TMASK;
      id[3] = (x0 ^ y1 ^ z1) & TMASK;
      id[4] = (x1 ^ y0 ^ z0) & TMASK;
      id[5] = (x1 ^ y0 ^ z1) & TMASK;
      id[6] = (x1 ^ y1 ^ z0) & TMASK;
      id[7] = (x1 ^ y1 ^ z1) & TMASK;
#pragma unroll
      for (int c = 0; c < 8; ++c)
        V[pt][c] = *(const uintx3*)(mtl + (size_t)id[c] * 3u);
    }
    __builtin_amdgcn_sched_barrier(0);

#pragma unroll
    for (int pt = 0; pt < 2; ++pt) {
      float dx = DX[pt], dy = DY[pt], dz = DZ[pt];
      float wx[2] = { 1.f - dx, dx }, wy[2] = { 1.f - dy, dy }, wz[2] = { 1.f - dz, dz };
      float a00 = 0.f, a01 = 0.f, a10 = 0.f, a11 = 0.f, a20 = 0.f, a21 = 0.f;
#pragma unroll
      for (int c = 0; c < 8; ++c) {
        float w = wx[c >> 2] * wy[(c >> 1) & 1] * wz[c & 1];
        unsigned int u0 = V[pt][c].x, u1 = V[pt][c].y, u2 = V[pt][c].z;
        a00 += bf2f(u0 << 16) * w;  a01 += bf2f(u0 & 0xFFFF0000u) * w;
        a10 += bf2f(u1 << 16) * w;  a11 += bf2f(u1 & 0xFFFF0000u) * w;
        a20 += bf2f(u2 << 16) * w;  a21 += bf2f(u2 & 0xFFFF0000u) * w;
      }
      unsigned int n = nbase + (unsigned int)(half * 512 + pt * 256);
      featws[f0 + n] = pack2(a00, a01);
      featws[f1 + n] = pack2(a10, a11);
      featws[f2b + n] = pack2(a20, a21);
    }
  }
}

// ---------------------------------------------------------------------------
// fp32 fallback (only if ws too small for merged tables): per-(table,level)
// ---------------------------------------------------------------------------
__global__ __launch_bounds__(256) void hash_f32(
    const float* __restrict__ p, const float* __restrict__ bound,
    const float* __restrict__ t0, const float* __restrict__ t1,
    const float* __restrict__ t2,
    unsigned int* __restrict__ featws, unsigned int* __restrict__ ctr,
    ResArr res)
{
  __shared__ int s_pad[10240];
  if (threadIdx.x == 0) {
    unsigned int xcc;
    asm volatile("s_getreg_b32 %0, hwreg(HW_REG_XCC_ID)" : "=s"(xcc));
    xcc &= 7u;
    int slot = -1;
    for (int k = 0; k < 8; ++k) {
      unsigned int q = (xcc + (unsigned int)k) & 7u;
      unsigned int s = atomicAdd(ctr + q, 1u);
      if (s < FQ_SLOTS) { slot = (int)(q * FQ_SLOTS + s); break; }
    }
    s_pad[0] = slot;
  }
  __syncthreads();
  int slot = s_pad[0];
  if (slot < 0) return;

  unsigned int q = (unsigned int)slot / FQ_SLOTS;
  unsigned int s = (unsigned int)slot - q * FQ_SLOTS;
  unsigned int i = (s >> 8) * 8u + q;
  unsigned int level = i / 3u;
  unsigned int table = i - level * 3u;
  unsigned int chunk = s & 255u;

  float r = res.r[0];
#pragma unroll
  for (int l = 1; l < 16; ++l) r = (level == (unsigned int)l) ? res.r[l] : r;

  float b0 = bound[0], b1 = bound[1], b2 = bound[2], b3 = bound[3],
        b4 = bound[4], b5 = bound[5];
  const float* tf = ((table == 0u) ? t0 : (table == 1u) ? t1 : t2) +
                    (size_t)level * (TTAB * 2);
  unsigned int fbase = (table * 16u + level) * (unsigned int)NPTS;
  unsigned int nbase = chunk * 1024u + threadIdx.x;

#pragma unroll
  for (int it = 0; it < 4; ++it) {
    unsigned int n = nbase + (unsigned int)it * 256u;
    float px = p[n * 3 + 0], py = p[n * 3 + 1], pz = p[n * 3 + 2];
    float x = (px - b0) / (b1 - b0);
    float y = (py - b2) / (b3 - b2);
    float z = (pz - b4) / (b5 - b4);
    float sx = x * r, sy = y * r, sz = z * r;
    float fx = floorf(sx), fy = floorf(sy), fz = floorf(sz);
    float dx = sx - fx, dy = sy - fy, dz = sz - fz;
    unsigned int cx = (unsigned int)fx, cy = (unsigned int)fy, cz = (unsigned int)fz;
    unsigned int hx[2] = { cx, cx + 1u };
    unsigned int hy[2] = { cy * PR1, (cy + 1u) * PR1 };
    unsigned int hz[2] = { cz * PR2, (cz + 1u) * PR2 };
    float wx[2] = { 1.f - dx, dx }, wy[2] = { 1.f - dy, dy }, wz[2] = { 1.f - dz, dz };
    float a0 = 0.f, a1 = 0.f;
#pragma unroll
    for (int ii = 0; ii < 2; ++ii)
#pragma unroll
      for (int jj = 0; jj < 2; ++jj)
#pragma unroll
        for (int kk = 0; kk < 2; ++kk) {
          unsigned int idx = (hx[ii] ^ hy[jj] ^ hz[kk]) & TMASK;
          float2 f2 = *(const float2*)(tf + (size_t)idx * 2);
          float w = wx[ii] * wy[jj] * wz[kk];
          a0 += f2.x * w;
          a1 += f2.y * w;
        }
    featws[fbase + n] = pack2(a0, a1);
  }
}

// ---------------------------------------------------------------------------
// Small MLPs (sdf chain + rgb) + plane_feat writeout. One thread per point.
// ---------------------------------------------------------------------------
__global__ __launch_bounds__(256) void mlp_small_kernel(
    const unsigned int* __restrict__ fws,
    const float* __restrict__ fw0, const float* __restrict__ fb0,
    const float* __restrict__ fw1, const float* __restrict__ fb1,
    const float* __restrict__ fw2, const float* __restrict__ fb2,
    const float* __restrict__ fw3, const float* __restrict__ fb3,
    const float* __restrict__ ow, const float* __restrict__ ob,
    const float* __restrict__ rw0, const float* __restrict__ rb0,
    const float* __restrict__ rw1, const float* __restrict__ rb1,
    float* __restrict__ out)
{
  unsigned int n = blockIdx.x * 256 + threadIdx.x;
  float ft[32], cf[32], sf[32];
#pragma unroll
  for (int l = 0; l < 16; ++l) {
    unsigned int u = fws[(0u * 16 + l) * (unsigned int)NPTS + n];
    ft[2 * l] = bf2f(u << 16); ft[2 * l + 1] = bf2f(u & 0xFFFF0000u);
    u = fws[(1u * 16 + l) * (unsigned int)NPTS + n];
    cf[2 * l] = bf2f(u << 16); cf[2 * l + 1] = bf2f(u & 0xFFFF0000u);
    u = fws[(2u * 16 + l) * (unsigned int)NPTS + n];
    sf[2 * l] = bf2f(u << 16); sf[2 * l + 1] = bf2f(u & 0xFFFF0000u);
  }

  // plane_feat = [c_feat[16:], f_feat[16:], s_feat[16:]] fp32
  {
    float* pf = out + (size_t)NPTS * 29 + (size_t)n * 48;
#pragma unroll
    for (int i2 = 0; i2 < 16; i2 += 4)
      *(float4*)(pf + i2) = make_float4(cf[16 + i2], cf[17 + i2], cf[18 + i2], cf[19 + i2]);
#pragma unroll
    for (int i2 = 0; i2 < 16; i2 += 4)
      *(float4*)(pf + 16 + i2) = make_float4(ft[16 + i2], ft[17 + i2], ft[18 + i2], ft[19 + i2]);
#pragma unroll
    for (int i2 = 0; i2 < 16; i2 += 4)
      *(float4*)(pf + 32 + i2) = make_float4(sf[16 + i2], sf[17 + i2], sf[18 + i2], sf[19 + i2]);
  }

  float h[16], g[16];
  for (int o = 0; o < 16; ++o) {
    float a = fb0[o];
    for (int i2 = 0; i2 < 32; ++i2) a += ft[i2] * fw0[o * 32 + i2];
    h[o] = fmaxf(a, 0.f);
  }
  for (int o = 0; o < 16; ++o) {
    float a = fb1[o];
    for (int i2 = 0; i2 < 16; ++i2) a += h[i2] * fw1[o * 16 + i2];
    g[o] = fmaxf(a, 0.f);
  }
  for (int o = 0; o < 16; ++o) {
    float a = fb2[o];
    for (int i2 = 0; i2 < 16; ++i2) a += g[i2] * fw2[o * 16 + i2];
    h[o] = fmaxf(a, 0.f);
  }
  for (int o = 0; o < 16; ++o) {
    float a = fb3[o];
    for (int i2 = 0; i2 < 16; ++i2) a += h[i2] * fw3[o * 16 + i2];
    g[o] = fmaxf(a, 0.f);
  }
  float so[17];
  for (int o = 0; o < 17; ++o) {
    float a = ob[o];
    for (int i2 = 0; i2 < 16; ++i2) a += g[i2] * ow[o * 16 + i2];
    so[o] = a;
  }
  float sdf = tanhf(so[0]);
  float rin[80];
#pragma unroll
  for (int i2 = 0; i2 < 16; ++i2) rin[i2] = so[i2 + 1];
#pragma unroll
  for (int i2 = 0; i2 < 32; ++i2) rin[16 + i2] = cf[i2];
#pragma unroll
  for (int i2 = 0; i2 < 32; ++i2) rin[48 + i2] = sf[i2];
  float hr[16];
  for (int o = 0; o < 16; ++o) {
    float a = rb0[o];
    for (int i2 = 0; i2 < 80; ++i2) a += rin[i2] * rw0[o * 80 + i2];
    hr[o] = fmaxf(a, 0.f);
  }
  float* po = out + (size_t)n * 29;
  for (int o = 0; o < 3; ++o) {
    float a = rb1[o];
    for (int i2 = 0; i2 < 16; ++i2) a += hr[i2] * rw1[o * 16 + i2];
    po[o] = 1.f / (1.f + expf(-a));
  }
  po[3] = sdf;
}

// ---------------------------------------------------------------------------
// Weight fp32 -> bf16 (semantic MLP; wo zero-padded 25->32 rows) + ctr zero.
// ---------------------------------------------------------------------------
__global__ __launch_bounds__(256) void cvt_kernel(
    const float* __restrict__ sw0, const float* __restrict__ sw1,
    const float* __restrict__ sw2, const float* __restrict__ swo,
    unsigned short* __restrict__ w0, unsigned short* __restrict__ w1,
    unsigned short* __restrict__ w2, unsigned short* __restrict__ wo,
    unsigned int* __restrict__ ctr)
{
  int t = blockIdx.x * 256 + threadIdx.x;   // grid covers 65536
  if (t < 8) ctr[t] = 0u;
  if (t < 8192) w0[t] = f2bf(sw0[t]);
  w1[t] = f2bf(sw1[t]);
  w2[t] = f2bf(sw2[t]);
  if (t < 8192) wo[t] = (t < 6400) ? f2bf(swo[t]) : (unsigned short)0;
}

// ---------------------------------------------------------------------------
// Semantic MLP 32->256->256->256->25 via bf16 MFMA 16x16x32.
// v2: SINGLE H buffer (33.8 KB LDS -> 4 blocks/CU, was 72.7 KB -> 2) with a
// read-barrier/write-barrier pair per layer instead of ping-pong; X staging
// removed (layer-0 A-frags loaded straight from featws, coalesced);
// __launch_bounds__(256,4) pins VGPR<=128 for 16 waves/CU; s_setprio(1)
// around MFMA clusters (phase diversity exists at 4 resident blocks).
// ---------------------------------------------------------------------------
#define LAYER256(Wp, Bp)                                                                   \
  {                                                                                        \
    _Pragma("unroll") for (int r = 0; r < 4; ++r)                                          \
      _Pragma("unroll") for (int c = 0; c < 4; ++c)                                        \
        acc[r][c] = (f32x4){0.f, 0.f, 0.f, 0.f};                                           \
    _Pragma("unroll") for (int c = 0; c < 4; ++c)                                          \
      bc[c] = *(const bf16x8*)(Wp + (size_t)(cw + c * 16 + l16) * 256 + quad * 8);         \
    _Pragma("unroll") for (int ks = 0; ks < 8; ++ks) {                                     \
      int k0 = ks * 32;                                                                    \
      if (ks < 7) {                                                                        \
        _Pragma("unroll") for (int c = 0; c < 4; ++c)                                      \
          bn[c] = *(const bf16x8*)(Wp + (size_t)(cw + c * 16 + l16) * 256 + k0 + 32 + quad * 8); \
      }                                                                                    \
      _Pragma("unroll") for (int r = 0; r < 4; ++r)                                        \
        a[r] = *(const bf16x8*)(H + (r * 16 + l16) * 264 + k0 + quad * 8);                 \
      __builtin_amdgcn_s_setprio(1);                                                       \
      _Pragma("unroll") for (int r = 0; r < 4; ++r)                                        \
        _Pragma("unroll") for (int c = 0; c < 4; ++c)                                      \
          acc[r][c] = __builtin_amdgcn_mfma_f32_16x16x32_bf16(a[r], bc[c], acc[r][c], 0, 0, 0); \
      __builtin_amdgcn_s_setprio(0);                                                       \
      _Pragma("unroll") for (int c = 0; c < 4; ++c) bc[c] = bn[c];                         \
    }                                                                                      \
    __syncthreads(); /* all waves done READING H */                                        \
    _Pragma("unroll") for (int c = 0; c < 4; ++c) {                                        \
      int col = cw + c * 16 + l16;                                                         \
      float bias = Bp[col];                                                                \
      _Pragma("unroll") for (int r = 0; r < 4; ++r)                                        \
        _Pragma("unroll") for (int g2 = 0; g2 < 4; ++g2) {                                 \
          int row = r * 16 + quad * 4 + g2;                                                \
          H[row * 264 + col] = f2bf(fmaxf(acc[r][c][g2] + bias, 0.f));                     \
        }                                                                                  \
    }                                                                                      \
    __syncthreads(); /* writes visible */                                                  \
  }

__global__ __launch_bounds__(256, 4) void sem_kernel(
    const unsigned int* __restrict__ fws,
    const unsigned short* __restrict__ w0, const unsigned short* __restrict__ w1,
    const unsigned short* __restrict__ w2, const unsigned short* __restrict__ wo,
    const float* __restrict__ b0, const float* __restrict__ b1,
    const float* __restrict__ b2, const float* __restrict__ bo,
    float* __restrict__ out)
{
  __shared__ alignas(16) unsigned short H[64 * 264];   // 33792 B -> 4 blocks/CU

  int tid = threadIdx.x;
  int n0 = blockIdx.x * 64;
  int lane = tid & 63, wv = tid >> 6;       // 4 waves
  int l16 = lane & 15, quad = lane >> 4;
  int cw = wv * 64;

  f32x4 acc[4][4];
  bf16x8 a[4], bc[4], bn[4];

  // ---- layer 0 (K=32): X direct-from-global @ W0^T -> H ----
  // A-frag row-tile r: dword d = featws[(32 + quad*4 + d)*NPTS + n0 + r*16 + l16]
#pragma unroll
  for (int r = 0; r < 4; ++r)
#pragma unroll
    for (int c = 0; c < 4; ++c) acc[r][c] = (f32x4){0.f, 0.f, 0.f, 0.f};
#pragma unroll
  for (int r = 0; r < 4; ++r) {
    unsigned int base = (32u + (unsigned int)quad * 4u) * (unsigned int)NPTS +
                        (unsigned int)(n0 + r * 16 + l16);
    U8 u;
    u.u.x = fws[base];
    u.u.y = fws[base + (unsigned int)NPTS];
    u.u.z = fws[base + 2u * (unsigned int)NPTS];
    u.u.w = fws[base + 3u * (unsigned int)NPTS];
    a[r] = u.v;
  }
#pragma unroll
  for (int c = 0; c < 4; ++c)
    bc[c] = *(const bf16x8*)(w0 + (size_t)(cw + c * 16 + l16) * 32 + quad * 8);
  __builtin_amdgcn_s_setprio(1);
#pragma unroll
  for (int r = 0; r < 4; ++r)
#pragma unroll
    for (int c = 0; c < 4; ++c)
      acc[r][c] = __builtin_amdgcn_mfma_f32_16x16x32_bf16(a[r], bc[c], acc[r][c], 0, 0, 0);
  __builtin_amdgcn_s_setprio(0);
#pragma unroll
  for (int c = 0; c < 4; ++c) {
    int col = cw + c * 16 + l16;
    float bias = b0[col];
#pragma unroll
    for (int r = 0; r < 4; ++r)
#pragma unroll
      for (int g2 = 0; g2 < 4; ++g2) {
        int row = r * 16 + quad * 4 + g2;
        H[row * 264 + col] = f2bf(fmaxf(acc[r][c][g2] + bias, 0.f));
      }
  }
  __syncthreads();

  // ---- layer 1: H @ W1^T -> H ----
  LAYER256(w1, b1)
  // ---- layer 2: H @ W2^T -> H ----
  LAYER256(w2, b2)

  // ---- output layer (25 cols): H @ Wo^T -> d_out ----
  // wave wv handles rows [wv*16, wv*16+16), cols 0..31
  {
    f32x4 acc2[2];
    acc2[0] = (f32x4){0.f, 0.f, 0.f, 0.f};
    acc2[1] = (f32x4){0.f, 0.f, 0.f, 0.f};
#pragma unroll
    for (int ks = 0; ks < 8; ++ks) {
      int k0 = ks * 32;
      bf16x8 af = *(const bf16x8*)(H + (wv * 16 + l16) * 264 + k0 + quad * 8);
#pragma unroll
      for (int c = 0; c < 2; ++c) {
        bf16x8 bf = *(const bf16x8*)(wo + (size_t)(c * 16 + l16) * 256 + k0 + quad * 8);
        acc2[c] = __builtin_amdgcn_mfma_f32_16x16x32_bf16(af, bf, acc2[c], 0, 0, 0);
      }
    }
#pragma unroll
    for (int c = 0; c < 2; ++c) {
      int col = c * 16 + l16;
      if (col < 25) {
        float bias = bo[col];
#pragma unroll
        for (int g2 = 0; g2 < 4; ++g2) {
          int row = wv * 16 + quad * 4 + g2;
          out[(size_t)(n0 + row) * 29 + 4 + col] = acc2[c][g2] + bias;
        }
      }
    }
  }
}

// ---------------------------------------------------------------------------
extern "C" void kernel_launch(void* const* d_in, const int* in_sizes, int n_in,
                              void* d_out, int out_size, void* d_ws, size_t ws_size,
                              hipStream_t stream) {
  const float* p      = (const float*)d_in[0];
  const float* bound  = (const float*)d_in[1];
  const float* t_sdf  = (const float*)d_in[2];
  const float* t_color= (const float*)d_in[3];
  const float* t_sem  = (const float*)d_in[4];
  const float* f_w0   = (const float*)d_in[5];
  const float* f_b0   = (const float*)d_in[6];
  const float* f_w1   = (const float*)d_in[7];
  const float* f_b1   = (const float*)d_in[8];
  const float* f_w2   = (const float*)d_in[9];
  const float* f_b2   = (const float*)d_in[10];
  const float* f_w3   = (const float*)d_in[11];
  const float* f_b3   = (const float*)d_in[12];
  const float* osdf_w = (const float*)d_in[13];
  const float* osdf_b = (const float*)d_in[14];
  const float* orgb_w0= (const float*)d_in[15];
  const float* orgb_b0= (const float*)d_in[16];
  const float* orgb_w1= (const float*)d_in[17];
  const float* orgb_b1= (const float*)d_in[18];
  const float* s_w0   = (const float*)d_in[19];
  const float* s_b0   = (const float*)d_in[20];
  const float* s_w1   = (const float*)d_in[21];
  const float* s_b1   = (const float*)d_in[22];
  const float* s_w2   = (const float*)d_in[23];
  const float* s_b2   = (const float*)d_in[24];
  const float* s_wo   = (const float*)d_in[25];
  const float* s_bo   = (const float*)d_in[26];

  unsigned int* featws = (unsigned int*)d_ws;                  // 48*N*4 = 50,331,648 B
  unsigned short* w0b = (unsigned short*)(featws + 48u * NPTS);
  unsigned short* w1b = w0b + 8192;
  unsigned short* w2b = w1b + 65536;
  unsigned short* wob = w2b + 65536;
  unsigned int* ctr = (unsigned int*)(wob + 8192);             // 32 B, 16-aligned
  unsigned int* mt = ctr + 8;                                  // 100,663,296 B
  size_t need_bt = ((char*)mt - (char*)d_ws) + (size_t)16 * TTAB * 12;
  bool use_bt = ws_size >= need_bt;

  ResArr res;
  double kk = (log(2048.0) - log(16.0)) / 15.0;
  for (int l = 0; l < 16; ++l) res.r[l] = (float)floor(16.0 * exp((double)l * kk));

  float* out = (float*)d_out;

  hipLaunchKernelGGL(cvt_kernel, dim3(256), dim3(256), 0, stream,
                     s_w0, s_w1, s_w2, s_wo, w0b, w1b, w2b, wob, ctr);
  if (use_bt) {
    hipLaunchKernelGGL(cvt_tab, dim3(32768), dim3(256), 0, stream,
                       t_sdf, t_color, t_sem, mt);
    hipLaunchKernelGGL(hash_merged, dim3(MHASH_BLOCKS), dim3(256), 0, stream,
                       p, bound, mt, featws, ctr, res);
  } else {
    hipLaunchKernelGGL(hash_f32, dim3(FHASH_BLOCKS), dim3(256), 0, stream,
                       p, bound, t_sdf, t_color, t_sem, featws, ctr, res);
  }
  hipLaunchKernelGGL(mlp_small_kernel, dim3(1024), dim3(256), 0, stream,
                     featws, f_w0, f_b0, f_w1, f_b1, f_w2, f_b2, f_w3, f_b3,
                     osdf_w, osdf_b, orgb_w0, orgb_b0, orgb_w1, orgb_b1, out);
  hipLaunchKernelGGL(sem_kernel, dim3(NPTS / 64), dim3(256), 0, stream,
                     featws, w0b, w1b, w2b, wob, s_b0, s_b1, s_b2, s_bo, out);
}

// Round 3
// 507.217 us; speedup vs baseline: 1.1548x; 1.1265x over previous
//
#include <hip/hip_runtime.h>
#include <math.h>

#define NPTS 262144
#define TTAB 524288
#define TMASK (TTAB - 1)
#define PR1 2654435761u
#define PR2 805459861u

// merged-table hash: 16 levels x 256 chunks, 2 levels per XCD queue
#define MQ_SLOTS 512
#define MHASH_BLOCKS (8 * MQ_SLOTS)
// fp32 fallback path (ws too small): 48 pairs x 256 chunks
#define FQ_SLOTS 1536
#define FHASH_BLOCKS (8 * FQ_SLOTS)

typedef __attribute__((ext_vector_type(4))) float f32x4;
typedef __attribute__((ext_vector_type(8))) short bf16x8;
typedef __attribute__((ext_vector_type(3))) unsigned int uintx3;

struct ResArr { float r[16]; };

__device__ __forceinline__ float bf2f(unsigned int u) {
  union { unsigned int i; float f; } v; v.i = u << 16; return v.f;
}
__device__ __forceinline__ unsigned short f2bf(float f) {
  union { float f; unsigned int i; } v; v.f = f;
  unsigned int r = v.i + 0x7FFFu + ((v.i >> 16) & 1u);
  return (unsigned short)(r >> 16);
}
__device__ __forceinline__ unsigned int pack2(float a, float b) {
  return (unsigned int)f2bf(a) | ((unsigned int)f2bf(b) << 16);
}

union U8 { uint4 u; bf16x8 v; };

// ---------------------------------------------------------------------------
// Tables fp32 -> merged packed-bf16: mt[(l*TTAB+idx)*3 + {sdf,color,sem}]
// One 12B entry holds all 3 tables' features for (level, idx).
// ---------------------------------------------------------------------------
__global__ __launch_bounds__(256) void cvt_tab(
    const float* __restrict__ t0, const float* __restrict__ t1,
    const float* __restrict__ t2, unsigned int* __restrict__ mt)
{
  size_t i = (size_t)blockIdx.x * 256 + threadIdx.x;   // l*TTAB + idx
  float2 a = ((const float2*)t0)[i];
  float2 b = ((const float2*)t1)[i];
  float2 c = ((const float2*)t2)[i];
  mt[i * 3 + 0] = pack2(a.x, a.y);
  mt[i * 3 + 1] = pack2(b.x, b.y);
  mt[i * 3 + 2] = pack2(c.x, c.y);
}

// ---------------------------------------------------------------------------
// Merged hash gather: one level per block-claim, XCD-affine queues.
// 8 x 12B dwordx3 gathers per point serve all 3 tables (3x fewer L2
// requests than per-table gathers). Level-major packed-bf16 features out.
// ---------------------------------------------------------------------------
__global__ __launch_bounds__(256) void hash_merged(
    const float* __restrict__ p, const float* __restrict__ bound,
    const unsigned int* __restrict__ mt,
    unsigned int* __restrict__ featws, unsigned int* __restrict__ ctr,
    ResArr res)
{
  __shared__ int s_slot;
  if (threadIdx.x == 0) {
    unsigned int xcc;
    asm volatile("s_getreg_b32 %0, hwreg(HW_REG_XCC_ID)" : "=s"(xcc));
    xcc &= 7u;
    int slot = -1;
    for (int k = 0; k < 8; ++k) {
      unsigned int q = (xcc + (unsigned int)k) & 7u;
      unsigned int s = atomicAdd(ctr + q, 1u);
      if (s < MQ_SLOTS) { slot = (int)(q * MQ_SLOTS + s); break; }
    }
    s_slot = slot;
  }
  __syncthreads();
  int slot = s_slot;
  if (slot < 0) return;

  unsigned int q = (unsigned int)slot / MQ_SLOTS;
  unsigned int s = (unsigned int)slot - q * MQ_SLOTS;
  unsigned int level = (s >> 8) * 8u + q;        // 0..15, queue q gets {q, q+8}
  unsigned int chunk = s & 255u;

  float r = res.r[0];
#pragma unroll
  for (int l = 1; l < 16; ++l) r = (level == (unsigned int)l) ? res.r[l] : r;

  float b0 = bound[0], b1 = bound[1], b2 = bound[2], b3 = bound[3],
        b4 = bound[4], b5 = bound[5];
  float i0v = 1.f / (b1 - b0), i1v = 1.f / (b3 - b2), i2v = 1.f / (b5 - b4);
  const unsigned int* mtl = mt + (size_t)level * TTAB * 3u;
  unsigned int f0 = (0u * 16u + level) * (unsigned int)NPTS;
  unsigned int f1 = (1u * 16u + level) * (unsigned int)NPTS;
  unsigned int f2b = (2u * 16u + level) * (unsigned int)NPTS;
  unsigned int nbase = chunk * 1024u + threadIdx.x;

#pragma unroll
  for (int half = 0; half < 2; ++half) {
    unsigned int CX[2], CY[2], CZ[2];
    float DX[2], DY[2], DZ[2];
#pragma unroll
    for (int pt = 0; pt < 2; ++pt) {
      unsigned int n = nbase + (unsigned int)(half * 512 + pt * 256);
      float px = p[n * 3 + 0], py = p[n * 3 + 1], pz = p[n * 3 + 2];
      float sx = (px - b0) * i0v * r;
      float sy = (py - b2) * i1v * r;
      float sz = (pz - b4) * i2v * r;
      float fx = floorf(sx), fy = floorf(sy), fz = floorf(sz);
      DX[pt] = sx - fx; DY[pt] = sy - fy; DZ[pt] = sz - fz;
      CX[pt] = (unsigned int)fx;
      CY[pt] = (unsigned int)fy * PR1;
      CZ[pt] = (unsigned int)fz * PR2;
    }
    __builtin_amdgcn_sched_barrier(0);

    uintx3 V[2][8];
#pragma unroll
    for (int pt = 0; pt < 2; ++pt) {
      unsigned int x0 = CX[pt], x1 = CX[pt] + 1u;
      unsigned int y0 = CY[pt], y1 = y0 + PR1;
      unsigned int z0 = CZ[pt], z1 = z0 + PR2;
      unsigned int id[8];
      id[0] = (x0 ^ y0 ^ z0) & TMASK;
      id[1] = (x0 ^ y0 ^ z1) & TMASK;
      id[2] = (x0 ^ y1 ^ z0) & TMASK;
      id[3] = (x0 ^ y1 ^ z1) & TMASK;
      id[4] = (x1 ^ y0 ^ z0) & TMASK;
      id[5] = (x1 ^ y0 ^ z1) & TMASK;
      id[6] = (x1 ^ y1 ^ z0) & TMASK;
      id[7] = (x1 ^ y1 ^ z1) & TMASK;
#pragma unroll
      for (int c = 0; c < 8; ++c)
        V[pt][c] = *(const uintx3*)(mtl + (size_t)id[c] * 3u);
    }
    __builtin_amdgcn_sched_barrier(0);

#pragma unroll
    for (int pt = 0; pt < 2; ++pt) {
      float dx = DX[pt], dy = DY[pt], dz = DZ[pt];
      float wx[2] = { 1.f - dx, dx }, wy[2] = { 1.f - dy, dy }, wz[2] = { 1.f - dz, dz };
      float a00 = 0.f, a01 = 0.f, a10 = 0.f, a11 = 0.f, a20 = 0.f, a21 = 0.f;
#pragma unroll
      for (int c = 0; c < 8; ++c) {
        float w = wx[c >> 2] * wy[(c >> 1) & 1] * wz[c & 1];
        unsigned int u0 = V[pt][c].x, u1 = V[pt][c].y, u2 = V[pt][c].z;
        a00 += bf2f(u0 << 16) * w;  a01 += bf2f(u0 & 0xFFFF0000u) * w;
        a10 += bf2f(u1 << 16) * w;  a11 += bf2f(u1 & 0xFFFF0000u) * w;
        a20 += bf2f(u2 << 16) * w;  a21 += bf2f(u2 & 0xFFFF0000u) * w;
      }
      unsigned int n = nbase + (unsigned int)(half * 512 + pt * 256);
      featws[f0 + n] = pack2(a00, a01);
      featws[f1 + n] = pack2(a10, a11);
      featws[f2b + n] = pack2(a20, a21);
    }
  }
}

// ---------------------------------------------------------------------------
// fp32 fallback (only if ws too small for merged tables): per-(table,level)
// ---------------------------------------------------------------------------
__global__ __launch_bounds__(256) void hash_f32(
    const float* __restrict__ p, const float* __restrict__ bound,
    const float* __restrict__ t0, const float* __restrict__ t1,
    const float* __restrict__ t2,
    unsigned int* __restrict__ featws, unsigned int* __restrict__ ctr,
    ResArr res)
{
  __shared__ int s_pad[10240];
  if (threadIdx.x == 0) {
    unsigned int xcc;
    asm volatile("s_getreg_b32 %0, hwreg(HW_REG_XCC_ID)" : "=s"(xcc));
    xcc &= 7u;
    int slot = -1;
    for (int k = 0; k < 8; ++k) {
      unsigned int q = (xcc + (unsigned int)k) & 7u;
      unsigned int s = atomicAdd(ctr + q, 1u);
      if (s < FQ_SLOTS) { slot = (int)(q * FQ_SLOTS + s); break; }
    }
    s_pad[0] = slot;
  }
  __syncthreads();
  int slot = s_pad[0];
  if (slot < 0) return;

  unsigned int q = (unsigned int)slot / FQ_SLOTS;
  unsigned int s = (unsigned int)slot - q * FQ_SLOTS;
  unsigned int i = (s >> 8) * 8u + q;
  unsigned int level = i / 3u;
  unsigned int table = i - level * 3u;
  unsigned int chunk = s & 255u;

  float r = res.r[0];
#pragma unroll
  for (int l = 1; l < 16; ++l) r = (level == (unsigned int)l) ? res.r[l] : r;

  float b0 = bound[0], b1 = bound[1], b2 = bound[2], b3 = bound[3],
        b4 = bound[4], b5 = bound[5];
  const float* tf = ((table == 0u) ? t0 : (table == 1u) ? t1 : t2) +
                    (size_t)level * (TTAB * 2);
  unsigned int fbase = (table * 16u + level) * (unsigned int)NPTS;
  unsigned int nbase = chunk * 1024u + threadIdx.x;

#pragma unroll
  for (int it = 0; it < 4; ++it) {
    unsigned int n = nbase + (unsigned int)it * 256u;
    float px = p[n * 3 + 0], py = p[n * 3 + 1], pz = p[n * 3 + 2];
    float x = (px - b0) / (b1 - b0);
    float y = (py - b2) / (b3 - b2);
    float z = (pz - b4) / (b5 - b4);
    float sx = x * r, sy = y * r, sz = z * r;
    float fx = floorf(sx), fy = floorf(sy), fz = floorf(sz);
    float dx = sx - fx, dy = sy - fy, dz = sz - fz;
    unsigned int cx = (unsigned int)fx, cy = (unsigned int)fy, cz = (unsigned int)fz;
    unsigned int hx[2] = { cx, cx + 1u };
    unsigned int hy[2] = { cy * PR1, (cy + 1u) * PR1 };
    unsigned int hz[2] = { cz * PR2, (cz + 1u) * PR2 };
    float wx[2] = { 1.f - dx, dx }, wy[2] = { 1.f - dy, dy }, wz[2] = { 1.f - dz, dz };
    float a0 = 0.f, a1 = 0.f;
#pragma unroll
    for (int ii = 0; ii < 2; ++ii)
#pragma unroll
      for (int jj = 0; jj < 2; ++jj)
#pragma unroll
        for (int kk = 0; kk < 2; ++kk) {
          unsigned int idx = (hx[ii] ^ hy[jj] ^ hz[kk]) & TMASK;
          float2 f2 = *(const float2*)(tf + (size_t)idx * 2);
          float w = wx[ii] * wy[jj] * wz[kk];
          a0 += f2.x * w;
          a1 += f2.y * w;
        }
    featws[fbase + n] = pack2(a0, a1);
  }
}

// ---------------------------------------------------------------------------
// Small MLPs (sdf chain + rgb) + plane_feat writeout. One thread per point.
// ---------------------------------------------------------------------------
__global__ __launch_bounds__(256) void mlp_small_kernel(
    const unsigned int* __restrict__ fws,
    const float* __restrict__ fw0, const float* __restrict__ fb0,
    const float* __restrict__ fw1, const float* __restrict__ fb1,
    const float* __restrict__ fw2, const float* __restrict__ fb2,
    const float* __restrict__ fw3, const float* __restrict__ fb3,
    const float* __restrict__ ow, const float* __restrict__ ob,
    const float* __restrict__ rw0, const float* __restrict__ rb0,
    const float* __restrict__ rw1, const float* __restrict__ rb1,
    float* __restrict__ out)
{
  unsigned int n = blockIdx.x * 256 + threadIdx.x;
  float ft[32], cf[32], sf[32];
#pragma unroll
  for (int l = 0; l < 16; ++l) {
    unsigned int u = fws[(0u * 16 + l) * (unsigned int)NPTS + n];
    ft[2 * l] = bf2f(u << 16); ft[2 * l + 1] = bf2f(u & 0xFFFF0000u);
    u = fws[(1u * 16 + l) * (unsigned int)NPTS + n];
    cf[2 * l] = bf2f(u << 16); cf[2 * l + 1] = bf2f(u & 0xFFFF0000u);
    u = fws[(2u * 16 + l) * (unsigned int)NPTS + n];
    sf[2 * l] = bf2f(u << 16); sf[2 * l + 1] = bf2f(u & 0xFFFF0000u);
  }

  // plane_feat = [c_feat[16:], f_feat[16:], s_feat[16:]] fp32
  {
    float* pf = out + (size_t)NPTS * 29 + (size_t)n * 48;
#pragma unroll
    for (int i2 = 0; i2 < 16; i2 += 4)
      *(float4*)(pf + i2) = make_float4(cf[16 + i2], cf[17 + i2], cf[18 + i2], cf[19 + i2]);
#pragma unroll
    for (int i2 = 0; i2 < 16; i2 += 4)
      *(float4*)(pf + 16 + i2) = make_float4(ft[16 + i2], ft[17 + i2], ft[18 + i2], ft[19 + i2]);
#pragma unroll
    for (int i2 = 0; i2 < 16; i2 += 4)
      *(float4*)(pf + 32 + i2) = make_float4(sf[16 + i2], sf[17 + i2], sf[18 + i2], sf[19 + i2]);
  }

  float h[16], g[16];
  for (int o = 0; o < 16; ++o) {
    float a = fb0[o];
    for (int i2 = 0; i2 < 32; ++i2) a += ft[i2] * fw0[o * 32 + i2];
    h[o] = fmaxf(a, 0.f);
  }
  for (int o = 0; o < 16; ++o) {
    float a = fb1[o];
    for (int i2 = 0; i2 < 16; ++i2) a += h[i2] * fw1[o * 16 + i2];
    g[o] = fmaxf(a, 0.f);
  }
  for (int o = 0; o < 16; ++o) {
    float a = fb2[o];
    for (int i2 = 0; i2 < 16; ++i2) a += g[i2] * fw2[o * 16 + i2];
    h[o] = fmaxf(a, 0.f);
  }
  for (int o = 0; o < 16; ++o) {
    float a = fb3[o];
    for (int i2 = 0; i2 < 16; ++i2) a += h[i2] * fw3[o * 16 + i2];
    g[o] = fmaxf(a, 0.f);
  }
  float so[17];
  for (int o = 0; o < 17; ++o) {
    float a = ob[o];
    for (int i2 = 0; i2 < 16; ++i2) a += g[i2] * ow[o * 16 + i2];
    so[o] = a;
  }
  float sdf = tanhf(so[0]);
  float rin[80];
#pragma unroll
  for (int i2 = 0; i2 < 16; ++i2) rin[i2] = so[i2 + 1];
#pragma unroll
  for (int i2 = 0; i2 < 32; ++i2) rin[16 + i2] = cf[i2];
#pragma unroll
  for (int i2 = 0; i2 < 32; ++i2) rin[48 + i2] = sf[i2];
  float hr[16];
  for (int o = 0; o < 16; ++o) {
    float a = rb0[o];
    for (int i2 = 0; i2 < 80; ++i2) a += rin[i2] * rw0[o * 80 + i2];
    hr[o] = fmaxf(a, 0.f);
  }
  float* po = out + (size_t)n * 29;
  for (int o = 0; o < 3; ++o) {
    float a = rb1[o];
    for (int i2 = 0; i2 < 16; ++i2) a += hr[i2] * rw1[o * 16 + i2];
    po[o] = 1.f / (1.f + expf(-a));
  }
  po[3] = sdf;
}

// ---------------------------------------------------------------------------
// Weight fp32 -> bf16 (semantic MLP; wo zero-padded 25->32 rows) + ctr zero.
// ---------------------------------------------------------------------------
__global__ __launch_bounds__(256) void cvt_kernel(
    const float* __restrict__ sw0, const float* __restrict__ sw1,
    const float* __restrict__ sw2, const float* __restrict__ swo,
    unsigned short* __restrict__ w0, unsigned short* __restrict__ w1,
    unsigned short* __restrict__ w2, unsigned short* __restrict__ wo,
    unsigned int* __restrict__ ctr)
{
  int t = blockIdx.x * 256 + threadIdx.x;   // grid covers 65536
  if (t < 8) ctr[t] = 0u;
  if (t < 8192) w0[t] = f2bf(sw0[t]);
  w1[t] = f2bf(sw1[t]);
  w2[t] = f2bf(sw2[t]);
  if (t < 8192) wo[t] = (t < 6400) ? f2bf(swo[t]) : (unsigned short)0;
}

// ---------------------------------------------------------------------------
// Semantic MLP 32->256->256->256->25 via bf16 MFMA 16x16x32.
// v3: M=128 per block, 8 waves; wave wv owns cols [wv*32, wv*32+32) x all
// 128 rows. Halves total weight re-read traffic (0.53 GB vs 1.06 GB; the
// v2 post-mortem showed correlated stalls on the L2/L3 weight stream, not
// occupancy). 2 weight loads per 16 MFMA (was 4), 2-deep weight prefetch
// (bc/bn/bn2) to cover ~500cy L3 latency. LDS 67.6 KB -> 2 blocks/CU =
// 16 waves/CU (same wave count as v2, isolating the traffic effect).
// ---------------------------------------------------------------------------
#define LAYER256(Wp, Bp)                                                                   \
  {                                                                                        \
    _Pragma("unroll") for (int r = 0; r < 8; ++r)                                          \
      _Pragma("unroll") for (int c = 0; c < 2; ++c)                                        \
        acc[r][c] = (f32x4){0.f, 0.f, 0.f, 0.f};                                           \
    _Pragma("unroll") for (int c = 0; c < 2; ++c) {                                        \
      bc[c] = *(const bf16x8*)(Wp + (size_t)(cw + c * 16 + l16) * 256 + quad * 8);         \
      bn[c] = *(const bf16x8*)(Wp + (size_t)(cw + c * 16 + l16) * 256 + 32 + quad * 8);    \
    }                                                                                      \
    _Pragma("unroll") for (int ks = 0; ks < 8; ++ks) {                                     \
      int k0 = ks * 32;                                                                    \
      if (ks < 6) {                                                                        \
        _Pragma("unroll") for (int c = 0; c < 2; ++c)                                      \
          bn2[c] = *(const bf16x8*)(Wp + (size_t)(cw + c * 16 + l16) * 256 + k0 + 64 + quad * 8); \
      }                                                                                    \
      __builtin_amdgcn_s_setprio(1);                                                       \
      _Pragma("unroll") for (int r = 0; r < 8; ++r) {                                      \
        bf16x8 av = *(const bf16x8*)(H + (r * 16 + l16) * 264 + k0 + quad * 8);            \
        acc[r][0] = __builtin_amdgcn_mfma_f32_16x16x32_bf16(av, bc[0], acc[r][0], 0, 0, 0);\
        acc[r][1] = __builtin_amdgcn_mfma_f32_16x16x32_bf16(av, bc[1], acc[r][1], 0, 0, 0);\
      }                                                                                    \
      __builtin_amdgcn_s_setprio(0);                                                       \
      _Pragma("unroll") for (int c = 0; c < 2; ++c) { bc[c] = bn[c]; bn[c] = bn2[c]; }     \
    }                                                                                      \
    __syncthreads(); /* all waves done READING H */                                        \
    _Pragma("unroll") for (int c = 0; c < 2; ++c) {                                        \
      int col = cw + c * 16 + l16;                                                         \
      float bias = Bp[col];                                                                \
      _Pragma("unroll") for (int r = 0; r < 8; ++r)                                        \
        _Pragma("unroll") for (int g2 = 0; g2 < 4; ++g2) {                                 \
          int row = r * 16 + quad * 4 + g2;                                                \
          H[row * 264 + col] = f2bf(fmaxf(acc[r][c][g2] + bias, 0.f));                     \
        }                                                                                  \
    }                                                                                      \
    __syncthreads(); /* writes visible */                                                  \
  }

__global__ __launch_bounds__(512, 4) void sem_kernel(
    const unsigned int* __restrict__ fws,
    const unsigned short* __restrict__ w0, const unsigned short* __restrict__ w1,
    const unsigned short* __restrict__ w2, const unsigned short* __restrict__ wo,
    const float* __restrict__ b0, const float* __restrict__ b1,
    const float* __restrict__ b2, const float* __restrict__ bo,
    float* __restrict__ out)
{
  __shared__ alignas(16) unsigned short H[128 * 264];   // 67584 B -> 2 blocks/CU

  int tid = threadIdx.x;
  int n0 = blockIdx.x * 128;
  int lane = tid & 63, wv = tid >> 6;       // 8 waves
  int l16 = lane & 15, quad = lane >> 4;
  int cw = wv * 32;                          // 32 cols per wave

  f32x4 acc[8][2];
  bf16x8 bc[2], bn[2], bn2[2];

  // ---- layer 0 (K=32): X direct-from-global @ W0^T -> H ----
#pragma unroll
  for (int r = 0; r < 8; ++r)
#pragma unroll
    for (int c = 0; c < 2; ++c) acc[r][c] = (f32x4){0.f, 0.f, 0.f, 0.f};
#pragma unroll
  for (int c = 0; c < 2; ++c)
    bc[c] = *(const bf16x8*)(w0 + (size_t)(cw + c * 16 + l16) * 32 + quad * 8);
#pragma unroll
  for (int r = 0; r < 8; ++r) {
    unsigned int base = (32u + (unsigned int)quad * 4u) * (unsigned int)NPTS +
                        (unsigned int)(n0 + r * 16 + l16);
    U8 u;
    u.u.x = fws[base];
    u.u.y = fws[base + (unsigned int)NPTS];
    u.u.z = fws[base + 2u * (unsigned int)NPTS];
    u.u.w = fws[base + 3u * (unsigned int)NPTS];
    acc[r][0] = __builtin_amdgcn_mfma_f32_16x16x32_bf16(u.v, bc[0], acc[r][0], 0, 0, 0);
    acc[r][1] = __builtin_amdgcn_mfma_f32_16x16x32_bf16(u.v, bc[1], acc[r][1], 0, 0, 0);
  }
#pragma unroll
  for (int c = 0; c < 2; ++c) {
    int col = cw + c * 16 + l16;
    float bias = b0[col];
#pragma unroll
    for (int r = 0; r < 8; ++r)
#pragma unroll
      for (int g2 = 0; g2 < 4; ++g2) {
        int row = r * 16 + quad * 4 + g2;
        H[row * 264 + col] = f2bf(fmaxf(acc[r][c][g2] + bias, 0.f));
      }
  }
  __syncthreads();

  // ---- layer 1: H @ W1^T -> H ----
  LAYER256(w1, b1)
  // ---- layer 2: H @ W2^T -> H ----
  LAYER256(w2, b2)

  // ---- output layer (25 cols): H @ Wo^T -> d_out ----
  // wave wv handles rows [wv*16, wv*16+16), cols 0..31
  {
    f32x4 acc2[2];
    acc2[0] = (f32x4){0.f, 0.f, 0.f, 0.f};
    acc2[1] = (f32x4){0.f, 0.f, 0.f, 0.f};
#pragma unroll
    for (int ks = 0; ks < 8; ++ks) {
      int k0 = ks * 32;
      bf16x8 af = *(const bf16x8*)(H + (wv * 16 + l16) * 264 + k0 + quad * 8);
#pragma unroll
      for (int c = 0; c < 2; ++c) {
        bf16x8 bfr = *(const bf16x8*)(wo + (size_t)(c * 16 + l16) * 256 + k0 + quad * 8);
        acc2[c] = __builtin_amdgcn_mfma_f32_16x16x32_bf16(af, bfr, acc2[c], 0, 0, 0);
      }
    }
#pragma unroll
    for (int c = 0; c < 2; ++c) {
      int col = c * 16 + l16;
      if (col < 25) {
        float bias = bo[col];
#pragma unroll
        for (int g2 = 0; g2 < 4; ++g2) {
          int row = wv * 16 + quad * 4 + g2;
          out[(size_t)(n0 + row) * 29 + 4 + col] = acc2[c][g2] + bias;
        }
      }
    }
  }
}

// ---------------------------------------------------------------------------
extern "C" void kernel_launch(void* const* d_in, const int* in_sizes, int n_in,
                              void* d_out, int out_size, void* d_ws, size_t ws_size,
                              hipStream_t stream) {
  const float* p      = (const float*)d_in[0];
  const float* bound  = (const float*)d_in[1];
  const float* t_sdf  = (const float*)d_in[2];
  const float* t_color= (const float*)d_in[3];
  const float* t_sem  = (const float*)d_in[4];
  const float* f_w0   = (const float*)d_in[5];
  const float* f_b0   = (const float*)d_in[6];
  const float* f_w1   = (const float*)d_in[7];
  const float* f_b1   = (const float*)d_in[8];
  const float* f_w2   = (const float*)d_in[9];
  const float* f_b2   = (const float*)d_in[10];
  const float* f_w3   = (const float*)d_in[11];
  const float* f_b3   = (const float*)d_in[12];
  const float* osdf_w = (const float*)d_in[13];
  const float* osdf_b = (const float*)d_in[14];
  const float* orgb_w0= (const float*)d_in[15];
  const float* orgb_b0= (const float*)d_in[16];
  const float* orgb_w1= (const float*)d_in[17];
  const float* orgb_b1= (const float*)d_in[18];
  const float* s_w0   = (const float*)d_in[19];
  const float* s_b0   = (const float*)d_in[20];
  const float* s_w1   = (const float*)d_in[21];
  const float* s_b1   = (const float*)d_in[22];
  const float* s_w2   = (const float*)d_in[23];
  const float* s_b2   = (const float*)d_in[24];
  const float* s_wo   = (const float*)d_in[25];
  const float* s_bo   = (const float*)d_in[26];

  unsigned int* featws = (unsigned int*)d_ws;                  // 48*N*4 = 50,331,648 B
  unsigned short* w0b = (unsigned short*)(featws + 48u * NPTS);
  unsigned short* w1b = w0b + 8192;
  unsigned short* w2b = w1b + 65536;
  unsigned short* wob = w2b + 65536;
  unsigned int* ctr = (unsigned int*)(wob + 8192);             // 32 B, 16-aligned
  unsigned int* mt = ctr + 8;                                  // 100,663,296 B
  size_t need_bt = ((char*)mt - (char*)d_ws) + (size_t)16 * TTAB * 12;
  bool use_bt = ws_size >= need_bt;

  ResArr res;
  double kk = (log(2048.0) - log(16.0)) / 15.0;
  for (int l = 0; l < 16; ++l) res.r[l] = (float)floor(16.0 * exp((double)l * kk));

  float* out = (float*)d_out;

  hipLaunchKernelGGL(cvt_kernel, dim3(256), dim3(256), 0, stream,
                     s_w0, s_w1, s_w2, s_wo, w0b, w1b, w2b, wob, ctr);
  if (use_bt) {
    hipLaunchKernelGGL(cvt_tab, dim3(32768), dim3(256), 0, stream,
                       t_sdf, t_color, t_sem, mt);
    hipLaunchKernelGGL(hash_merged, dim3(MHASH_BLOCKS), dim3(256), 0, stream,
                       p, bound, mt, featws, ctr, res);
  } else {
    hipLaunchKernelGGL(hash_f32, dim3(FHASH_BLOCKS), dim3(256), 0, stream,
                       p, bound, t_sdf, t_color, t_sem, featws, ctr, res);
  }
  hipLaunchKernelGGL(mlp_small_kernel, dim3(1024), dim3(256), 0, stream,
                     featws, f_w0, f_b0, f_w1, f_b1, f_w2, f_b2, f_w3, f_b3,
                     osdf_w, osdf_b, orgb_w0, orgb_b0, orgb_w1, orgb_b1, out);
  hipLaunchKernelGGL(sem_kernel, dim3(NPTS / 128), dim3(512), 0, stream,
                     featws, w0b, w1b, w2b, wob, s_b0, s_b1, s_b2, s_bo, out);
}